// Round 9
// baseline (66.136 us; speedup 1.0000x reference)
//
#include <hip/hip_runtime.h>
#include <hip/hip_bf16.h>

#define BB 16
#define TT 2048
#define DD 384
#define GG 2048          // total chains = BB * 128
#define CC 512           // chunks over T
#define LL 4             // steps per chunk (CC*LL == TT)
#define OCT 8            // chunks per lane in fused scan (OCT*64 == CC)
#define HSTRIDE (DD + 8) // 392 ≡ 8 (mod 32): conflict-free LDS access
#define SROW 21          // odd word stride for scan-staging LDS (coprime with 32)
#define EPSF 1e-8f
#define RCPF(x) __builtin_amdgcn_rcpf(x)

// ---------- kernel 0: combined weights Wc[m][k][j] = sum_d W_in[k][d]*Wm[d][j] ----------
__global__ __launch_bounds__(256) void precompute_wc(
        const float* __restrict__ W_in,
        const float* __restrict__ W_biv,
        const float* __restrict__ W_dec,
        const float* __restrict__ W_inj,
        float* __restrict__ Wc) {
    int m = blockIdx.x;
    int jl = threadIdx.x & 15;
    int dp = threadIdx.x >> 4;           // 0..15
    int j = blockIdx.y * 16 + jl;
    const float* __restrict__ W = (m == 0) ? W_biv : (m == 1) ? W_dec : W_inj;
    float a[4] = {0.f, 0.f, 0.f, 0.f};
    for (int d = dp; d < DD; d += 16) {
        float wv = W[d * DD + j];
#pragma unroll
        for (int k = 0; k < 4; ++k) a[k] = fmaf(W_in[k * DD + d], wv, a[k]);
    }
    __shared__ float red[16][17][4];
#pragma unroll
    for (int k = 0; k < 4; ++k) red[dp][jl][k] = a[k];
    __syncthreads();
    for (int s = 8; s >= 1; s >>= 1) {
        if (dp < s) {
#pragma unroll
            for (int k = 0; k < 4; ++k) red[dp][jl][k] += red[dp + s][jl][k];
        }
        __syncthreads();
    }
    if (dp < 4)
        Wc[(size_t)m * 4 * DD + dp * DD + j] = red[0][jl][dp];
}

// ---------- per-chain weights & per-step math (polynomial trig) ----------
struct Wts {
    float wb[4][3], wd[4][3], wi[4][3];
    float bb[3], bd[3], bj[3];
};

__device__ __forceinline__ void load_wts(const float* __restrict__ Wc,
                                         const float* __restrict__ b_biv,
                                         const float* __restrict__ b_dec,
                                         const float* __restrict__ b_inj,
                                         int j0, Wts& W) {
    const float* __restrict__ Wb = Wc;
    const float* __restrict__ Wd = Wc + 4 * DD;
    const float* __restrict__ Wi = Wc + 8 * DD;
#pragma unroll
    for (int k = 0; k < 4; ++k)
#pragma unroll
        for (int c = 0; c < 3; ++c) {
            W.wb[k][c] = Wb[k * DD + j0 + c];
            W.wd[k][c] = Wd[k * DD + j0 + c];
            W.wi[k][c] = Wi[k * DD + j0 + c];
        }
#pragma unroll
    for (int c = 0; c < 3; ++c) {
        W.bb[c] = b_biv[j0 + c];
        W.bd[c] = b_dec[j0 + c];
        W.bj[c] = b_inj[j0 + c];
    }
}

#define DOTW(M, c, bias) \
    fmaf(q.w, W.M[3][c], fmaf(q.z, W.M[2][c], fmaf(q.y, W.M[1][c], fmaf(q.x, W.M[0][c], bias))))

// w = cos(nb/2) ~ 1 - u/8 + u^2/384 ; s = sin(nb/2)/nb ~ 1/2 - u/48 + u^2/3840 ; u = nb^2.
__device__ __forceinline__ void step_parts(const Wts& W, float4 q,
        float& dec0, float& dec1, float& dec2,
        float& w, float& qx, float& qy, float& qz,
        float& i0, float& i1, float& i2) {
    float bx = DOTW(wb, 0, W.bb[0]);
    float by = DOTW(wb, 1, W.bb[1]);
    float bz = DOTW(wb, 2, W.bb[2]);
    float d0 = DOTW(wd, 0, W.bd[0]);
    float d1 = DOTW(wd, 1, W.bd[1]);
    float d2 = DOTW(wd, 2, W.bd[2]);
    i0 = DOTW(wi, 0, W.bj[0]);
    i1 = DOTW(wi, 1, W.bj[1]);
    i2 = DOTW(wi, 2, W.bj[2]);
    dec0 = RCPF(1.f + __expf(-d0));
    dec1 = RCPF(1.f + __expf(-d1));
    dec2 = RCPF(1.f + __expf(-d2));
    float u = fmaf(bx, bx, fmaf(by, by, bz * bz));
    w = fmaf(u, fmaf(u, 2.6041667e-3f, -0.125f), 1.f);
    float s = fmaf(u, fmaf(u, 2.6041667e-4f, -2.0833333e-2f), 0.5f);
    qx = s * bz; qy = -s * by; qz = s * bx;
}

// affine map as 12-vec: A row-major [0..8], d [9..11]; this step's map composed onto A
__device__ __forceinline__ void step_compose12(const Wts& W, float4 q, float A[12]) {
    float dec0, dec1, dec2, w, qx, qy, qz, i0, i1, i2;
    step_parts(W, q, dec0, dec1, dec2, w, qx, qy, qz, i0, i1, i2);
    float xx = qx*qx, yy = qy*qy, zz = qz*qz;
    float xy = qx*qy, xz = qx*qz, yz = qy*qz;
    float wxs = w*qx, wys = w*qy, wzs = w*qz;
    float M0 = dec0 * (1.f - 2.f*(yy+zz));
    float M1 = dec0 * (2.f*(xy - wzs));
    float M2 = dec0 * (2.f*(xz + wys));
    float M3 = dec1 * (2.f*(xy + wzs));
    float M4 = dec1 * (1.f - 2.f*(xx+zz));
    float M5 = dec1 * (2.f*(yz - wxs));
    float M6 = dec2 * (2.f*(xz - wys));
    float M7 = dec2 * (2.f*(yz + wxs));
    float M8 = dec2 * (1.f - 2.f*(xx+yy));
    float n0 = fmaf(M0, A[0], fmaf(M1, A[3], M2 * A[6]));
    float n1 = fmaf(M0, A[1], fmaf(M1, A[4], M2 * A[7]));
    float n2 = fmaf(M0, A[2], fmaf(M1, A[5], M2 * A[8]));
    float n3 = fmaf(M3, A[0], fmaf(M4, A[3], M5 * A[6]));
    float n4 = fmaf(M3, A[1], fmaf(M4, A[4], M5 * A[7]));
    float n5 = fmaf(M3, A[2], fmaf(M4, A[5], M5 * A[8]));
    float n6 = fmaf(M6, A[0], fmaf(M7, A[3], M8 * A[6]));
    float n7 = fmaf(M6, A[1], fmaf(M7, A[4], M8 * A[7]));
    float n8 = fmaf(M6, A[2], fmaf(M7, A[5], M8 * A[8]));
    float n9  = fmaf(M0, A[9], fmaf(M1, A[10], fmaf(M2, A[11], i0)));
    float n10 = fmaf(M3, A[9], fmaf(M4, A[10], fmaf(M5, A[11], i1)));
    float n11 = fmaf(M6, A[9], fmaf(M7, A[10], fmaf(M8, A[11], i2)));
    A[0]=n0; A[1]=n1; A[2]=n2; A[3]=n3; A[4]=n4; A[5]=n5;
    A[6]=n6; A[7]=n7; A[8]=n8; A[9]=n9; A[10]=n10; A[11]=n11;
}

__device__ __forceinline__ void step_apply(const Wts& W, float4 q,
                                           float& vx, float& vy, float& vz) {
    float dec0, dec1, dec2, w, qx, qy, qz, i0, i1, i2;
    step_parts(W, q, dec0, dec1, dec2, w, qx, qy, qz, i0, i1, i2);
    float tx = 2.f * (qy * vz - qz * vy);
    float ty = 2.f * (qz * vx - qx * vz);
    float tz = 2.f * (qx * vy - qy * vx);
    float rx = vx + w * tx + (qy * tz - qz * ty);
    float ry = vy + w * ty + (qz * tx - qx * tz);
    float rz = vz + w * tz + (qx * ty - qy * tx);
    vx = fmaf(dec0, rx, i0);
    vy = fmaf(dec1, ry, i1);
    vz = fmaf(dec2, rz, i2);
}

// R = C ∘ P   (12-vec affine maps)
#define COMPOSE(R, C, P)                                                    \
    R[0] = fmaf(C[0], P[0], fmaf(C[1], P[3], C[2] * P[6]));                 \
    R[1] = fmaf(C[0], P[1], fmaf(C[1], P[4], C[2] * P[7]));                 \
    R[2] = fmaf(C[0], P[2], fmaf(C[1], P[5], C[2] * P[8]));                 \
    R[3] = fmaf(C[3], P[0], fmaf(C[4], P[3], C[5] * P[6]));                 \
    R[4] = fmaf(C[3], P[1], fmaf(C[4], P[4], C[5] * P[7]));                 \
    R[5] = fmaf(C[3], P[2], fmaf(C[4], P[5], C[5] * P[8]));                 \
    R[6] = fmaf(C[6], P[0], fmaf(C[7], P[3], C[8] * P[6]));                 \
    R[7] = fmaf(C[6], P[1], fmaf(C[7], P[4], C[8] * P[7]));                 \
    R[8] = fmaf(C[6], P[2], fmaf(C[7], P[5], C[8] * P[8]));                 \
    R[9]  = fmaf(C[0], P[9], fmaf(C[1], P[10], fmaf(C[2], P[11], C[9])));   \
    R[10] = fmaf(C[3], P[9], fmaf(C[4], P[10], fmaf(C[5], P[11], C[10])));  \
    R[11] = fmaf(C[6], P[9], fmaf(C[7], P[10], fmaf(C[8], P[11], C[11])));

// ---------- fused kernel: compose all chunk maps + wave scan -> chunk start states ----------
// one wave per chain; lane l owns chunks 8l..8l+7 (4-way ILP in two batches);
// Hs layout: [CC][GG] float4 (xyz = start state), written block-coalesced via LDS transpose.
__global__ __launch_bounds__(256) void compose_scan(
        const float* __restrict__ quat,
        const float* __restrict__ Wc,
        const float* __restrict__ b_biv,
        const float* __restrict__ b_dec,
        const float* __restrict__ b_inj,
        float4* __restrict__ Hs) {
    int wave = threadIdx.x >> 6, l = threadIdx.x & 63;
    int g = blockIdx.x * 4 + wave;
    int b = g >> 7, n = g & 127, j0 = 3 * n;
    Wts W;
    load_wts(Wc, b_biv, b_dec, b_inj, j0, W);

    const float4* __restrict__ qp = (const float4*)(quat + (size_t)b * TT * 4);

    float m[OCT][12];
#pragma unroll
    for (int batch = 0; batch < 2; ++batch) {
        float A[4][12];
#pragma unroll
        for (int kk = 0; kk < 4; ++kk) {
            A[kk][0]=1.f; A[kk][1]=0.f; A[kk][2]=0.f; A[kk][3]=0.f; A[kk][4]=1.f; A[kk][5]=0.f;
            A[kk][6]=0.f; A[kk][7]=0.f; A[kk][8]=1.f; A[kk][9]=0.f; A[kk][10]=0.f; A[kk][11]=0.f;
        }
#pragma unroll
        for (int t = 0; t < LL; ++t) {
#pragma unroll
            for (int kk = 0; kk < 4; ++kk) {
                int c = OCT * l + batch * 4 + kk;
                step_compose12(W, qp[c * LL + t], A[kk]);
            }
        }
#pragma unroll
        for (int kk = 0; kk < 4; ++kk)
#pragma unroll
            for (int e = 0; e < 12; ++e) m[batch * 4 + kk][e] = A[kk][e];
    }

    // octet composite Q = m7 ∘ ... ∘ m0
    float Q[12], Tq[12];
#pragma unroll
    for (int e = 0; e < 12; ++e) Q[e] = m[0][e];
#pragma unroll
    for (int k = 1; k < OCT; ++k) {
        COMPOSE(Tq, m[k], Q);
#pragma unroll
        for (int e = 0; e < 12; ++e) Q[e] = Tq[e];
    }

    // Kogge-Stone exclusive prefix over lanes
    float P[12];
#pragma unroll
    for (int e = 0; e < 12; ++e) P[e] = __shfl_up(Q[e], 1);
    if (l == 0) {
        P[0]=1.f; P[1]=0.f; P[2]=0.f; P[3]=0.f; P[4]=1.f; P[5]=0.f;
        P[6]=0.f; P[7]=0.f; P[8]=1.f; P[9]=0.f; P[10]=0.f; P[11]=0.f;
    }
#pragma unroll
    for (int sft = 1; sft < 64; sft <<= 1) {
        float S[12], N[12];
#pragma unroll
        for (int e = 0; e < 12; ++e) S[e] = __shfl_up(P[e], sft);
        COMPOSE(N, P, S);
        bool act = (l >= sft);
#pragma unroll
        for (int e = 0; e < 12; ++e) P[e] = act ? N[e] : P[e];
    }

    // emit chunk starts to LDS (odd stride SROW -> ≤2-way banks), then coalesced global store
    __shared__ float SL[CC * SROW];   // 512*21*4B = 43008 B
    float h0 = P[9], h1 = P[10], h2 = P[11];
#pragma unroll
    for (int k = 0; k < OCT; ++k) {
        int c = OCT * l + k;
        float* s = SL + c * SROW + wave * 4;
        s[0] = h0; s[1] = h1; s[2] = h2; s[3] = 0.f;
        if (k < OCT - 1) {
            float t0 = fmaf(m[k][0], h0, fmaf(m[k][1], h1, fmaf(m[k][2], h2, m[k][9])));
            float t1 = fmaf(m[k][3], h0, fmaf(m[k][4], h1, fmaf(m[k][5], h2, m[k][10])));
            float t2 = fmaf(m[k][6], h0, fmaf(m[k][7], h1, fmaf(m[k][8], h2, m[k][11])));
            h0 = t0; h1 = t1; h2 = t2;
        }
    }
    __syncthreads();
    int g0 = blockIdx.x * 4;
#pragma unroll
    for (int e = threadIdx.x; e < CC * 4; e += 256) {
        int c = e >> 2, w = e & 3;
        const float* s = SL + c * SROW + w * 4;
        Hs[(size_t)c * GG + g0 + w] = make_float4(s[0], s[1], s[2], s[3]);
    }
}

// ---------- kernel C: fused replay + out-projection via LDS, ONE barrier ----------
__global__ __launch_bounds__(128) void chunk_apply_out(
        const float* __restrict__ quat,
        const float* __restrict__ Wc,
        const float* __restrict__ b_biv,
        const float* __restrict__ b_dec,
        const float* __restrict__ b_inj,
        const float* __restrict__ W_out,   // [DD][4]
        const float4* __restrict__ Hs,     // [CC][GG]
        float* __restrict__ out) {         // [BB][TT][4]
    int c = blockIdx.x, b = blockIdx.y, n = threadIdx.x;
    int g = b * 128 + n, j0 = 3 * n;
    Wts W;
    load_wts(Wc, b_biv, b_dec, b_inj, j0, W);

    __shared__ float H[LL][HSTRIDE];

    float4 hv4 = Hs[(size_t)c * GG + g];
    float vx = hv4.x, vy = hv4.y, vz = hv4.z;

    const float4* __restrict__ qp4 = (const float4*)(quat + (size_t)b * TT * 4) + c * LL;

#pragma unroll
    for (int t = 0; t < LL; ++t) {
        step_apply(W, qp4[t], vx, vy, vz);
        H[t][j0] = vx; H[t][j0 + 1] = vy; H[t][j0 + 2] = vz;
    }
    __syncthreads();

    // projection: thread -> (row r = n>>5, part p = n&31); d = p + 32j
    int r = n >> 5, p = n & 31;
    float s0 = 0.f, s1 = 0.f, s2 = 0.f, s3 = 0.f;
#pragma unroll
    for (int j = 0; j < DD / 32; ++j) {
        int d = p + 32 * j;
        float hv = H[r][d];
        float4 wv = *(const float4*)(W_out + (size_t)d * 4);
        s0 = fmaf(hv, wv.x, s0);
        s1 = fmaf(hv, wv.y, s1);
        s2 = fmaf(hv, wv.z, s2);
        s3 = fmaf(hv, wv.w, s3);
    }
#pragma unroll
    for (int off = 1; off <= 16; off <<= 1) {
        s0 += __shfl_xor(s0, off);
        s1 += __shfl_xor(s1, off);
        s2 += __shfl_xor(s2, off);
        s3 += __shfl_xor(s3, off);
    }
    if (p == 0) {
        float norm = fmaxf(sqrtf(fmaf(s0, s0, fmaf(s1, s1, fmaf(s2, s2, s3 * s3)))), EPSF);
        float inv = RCPF(norm);
        float* outp = out + ((size_t)b * TT + (size_t)c * LL + r) * 4;
        *(float4*)outp = make_float4(s0 * inv, s1 * inv, s2 * inv, s3 * inv);
    }
}

extern "C" void kernel_launch(void* const* d_in, const int* in_sizes, int n_in,
                              void* d_out, int out_size, void* d_ws, size_t ws_size,
                              hipStream_t stream) {
    const float* quat  = (const float*)d_in[0];
    const float* W_in  = (const float*)d_in[1];
    const float* W_biv = (const float*)d_in[2];
    const float* b_biv = (const float*)d_in[3];
    const float* W_dec = (const float*)d_in[4];
    const float* b_dec = (const float*)d_in[5];
    const float* W_inj = (const float*)d_in[6];
    const float* b_inj = (const float*)d_in[7];
    const float* W_out = (const float*)d_in[8];
    float* out = (float*)d_out;

    float*  Wc = (float*)d_ws;                            // 4608 floats
    float4* Hs = (float4*)((char*)d_ws + 32768);          // CC*GG float4 = 16.8 MB

    precompute_wc<<<dim3(3, DD / 16), dim3(256), 0, stream>>>(W_in, W_biv, W_dec, W_inj, Wc);
    compose_scan<<<dim3(GG / 4), dim3(256), 0, stream>>>(quat, Wc, b_biv, b_dec, b_inj, Hs);
    chunk_apply_out<<<dim3(CC, BB), dim3(128), 0, stream>>>(quat, Wc, b_biv, b_dec, b_inj,
                                                            W_out, Hs, out);
}